// Round 6
// baseline (593.342 us; speedup 1.0000x reference)
//
#include <hip/hip_runtime.h>
#include <stdint.h>

typedef __attribute__((ext_vector_type(8))) short short8;
typedef __attribute__((ext_vector_type(4))) float f32x4;
typedef __attribute__((ext_vector_type(4))) unsigned int u32x4;

#define KDIM 8192
#define NDIM 8192
#define MDIM 64
#define NGRP 128
#define KT 64                  // output rows per block (16 per wave)
#define SPLIT 8                // split-K partials per output
#define NCHUNK (NDIM / SPLIT)  // 1024 input features per block
#define NSTEPS (NCHUNK / 64)   // 16 quant groups per block
#define XFRAG (MDIM * NDIM)    // shorts per x-fragment buffer (1 MB)
#define MK (MDIM * KDIM)       // floats per output / partial slab (2 MB)

// LDS carve (total exactly 65536 B):
#define MB_OFF 0       // mask: 2 bufs x (4 waves x 4 KB) = 32 KB
#define WQ_OFF 32768   // wq:   2 bufs x (4 waves x 1 KB) = 8 KB
#define XF_OFF 40960   // xf:   8 tiles x 2 KB (H+L)      = 16 KB (block-shared)
#define SC_OFF 57344   // scales/zeros: 4 waves x 2 KB    = 8 KB
#define LDS_BYTES 65536

#define AS3 __attribute__((address_space(3)))
#define AS1 __attribute__((address_space(1)))

__device__ __forceinline__ short f2bf(float v) {
  unsigned u = __builtin_bit_cast(unsigned, v);
  u += 0x7FFFu + ((u >> 16) & 1u);  // round-to-nearest-even
  return (short)(u >> 16);
}
__device__ __forceinline__ float bf2f(short h) {
  unsigned u = ((unsigned)(unsigned short)h) << 16;
  return __builtin_bit_cast(float, u);
}

// out[m,k] = bias[k]  (atomic-path init)
__global__ void init_out_kernel(const float* __restrict__ bias, float* __restrict__ out) {
  int i = blockIdx.x * blockDim.x + threadIdx.x;
  f32x4 b = ((const f32x4*)bias)[i & (KDIM / 4 - 1)];
  ((f32x4*)out)[i] = b;
}

// out[m,k] = bias[k] + sum_s pw[s][m][k]
__global__ void reduce_kernel(const float* __restrict__ pw, const float* __restrict__ bias,
                              float* __restrict__ out) {
  int i = blockIdx.x * blockDim.x + threadIdx.x;  // 131072 float4
  f32x4 acc = ((const f32x4*)bias)[i & (KDIM / 4 - 1)];
#pragma unroll
  for (int s = 0; s < SPLIT; ++s) acc += ((const f32x4*)pw)[s * (MK / 4) + i];
  ((f32x4*)out)[i] = acc;
}

// x' = x*mu1 split into bf16 high (xfH) + bf16 residual (xfL), MFMA A-frag order with
// the k-permute: frag F = g*2+sub (g = feature group of 64): lane l holds
// x'[mblk*16+(l&15)][g*64 + (l>>4)*16 + sub*8 + i], i=0..7.
__global__ void prep_xf_kernel(const float* __restrict__ x, const float* __restrict__ mu1,
                               short* __restrict__ xfH, short* __restrict__ xfL) {
  int tid = blockIdx.x * blockDim.x + threadIdx.x;  // 65536 threads
  int l = tid & 63;
  int mblk = (tid >> 6) & 3;
  int g = tid >> 9;
  int sub = (tid >> 8) & 1;
  int m = mblk * 16 + (l & 15);
  int nb = g * 64 + (l >> 4) * 16 + sub * 8;  // 8 contiguous floats, 32B aligned
  const float* xr = x + (size_t)m * NDIM + nb;
  f32x4 x0 = *(const f32x4*)xr;
  f32x4 x1 = *(const f32x4*)(xr + 4);
  f32x4 u0 = *(const f32x4*)(mu1 + nb);
  f32x4 u1 = *(const f32x4*)(mu1 + nb + 4);
  short8 hv, lv;
#pragma unroll
  for (int i = 0; i < 8; ++i) {
    float xv = (i < 4) ? x0[i & 3] * u0[i & 3] : x1[i & 3] * u1[i & 3];
    short h = f2bf(xv);
    hv[i] = h;
    lv[i] = f2bf(xv - bf2f(h));
  }
  *(short8*)(xfH + (size_t)tid * 8) = hv;
  *(short8*)(xfL + (size_t)tid * 8) = lv;
}

// ---------------- hot path: int8 W_q, global_load_lds pipeline ----------------

template <bool ATOMIC>
__device__ __forceinline__ void gemm_body_i8(const uint8_t* __restrict__ wq,
                                             const float* __restrict__ scales,
                                             const float* __restrict__ zeros,
                                             const float* __restrict__ mask,
                                             const float* __restrict__ mu2,
                                             const short* __restrict__ xfH,
                                             const short* __restrict__ xfL,
                                             float* __restrict__ outp, char* smem) {
  const int bx = blockIdx.x;
  const int kt = bx >> 3;
  const int s = bx & 7;
  const int k0 = kt * KT;
  const int n0 = s * NCHUNK;
  const int tid = threadIdx.x;
  const int w = tid >> 6;  // wave id
  const int l = tid & 63;
  const int r = l & 15;   // output row within wave tile
  const int g4 = l >> 4;  // k-quad
  const int kc = k0 + w * 16 + r;
  const float mu2k = mu2[kc];

  AS3 char* lb = (AS3 char*)smem;

  // staging source bases (per lane)
  const float* msrc = mask + (size_t)kc * NDIM + n0 + (l >> 4) * 4;
  const uint8_t* qsrc = wq + (size_t)kc * NDIM + n0 + (l >> 4) * 16;
  const float* ssrc = scales + (size_t)(k0 + w * 16 + (l >> 2)) * NGRP + (n0 >> 6) + (l & 3) * 4;
  const float* zsrc = zeros + (size_t)(k0 + w * 16 + (l >> 2)) * NGRP + (n0 >> 6) + (l & 3) * 4;
  const int nb0 = s * 32;

#define GLDS16(gp, loff) \
  __builtin_amdgcn_global_load_lds((const AS1 void*)(gp), (AS3 void*)(lb + (loff)), 16, 0, 0)

#define STAGE_MW(st_, buf_)                                                            \
  do {                                                                                 \
    const float* mp_ = msrc + (st_) * 64;                                              \
    _Pragma("unroll") for (int q_ = 0; q_ < 4; ++q_)                                   \
        GLDS16(mp_ + q_ * 16, MB_OFF + (buf_) * 16384 + w * 4096 + q_ * 1024);         \
    GLDS16(qsrc + (st_) * 64, WQ_OFF + (buf_) * 4096 + w * 1024);                      \
  } while (0)

#define STAGE_XF(st_)                                                                  \
  do {                                                                                 \
    _Pragma("unroll") for (int ii_ = 0; ii_ < 4; ++ii_) {                              \
      int t_ = 2 * w + (ii_ >> 1);                                                     \
      int hl_ = ii_ & 1;                                                               \
      int F_ = (nb0 + (st_) * 2 + (t_ >> 2));                                          \
      const short* sp_ = (hl_ ? xfL : xfH) + ((size_t)F_ * 256 + (t_ & 3) * 64 + l) * 8; \
      GLDS16(sp_, XF_OFF + t_ * 2048 + hl_ * 1024);                                    \
    }                                                                                  \
  } while (0)

  // ---- prologue: sc(2) + xf0(4) + mw0(5) + mw1(5) = 16 outstanding ----
  GLDS16(ssrc, SC_OFF + w * 2048);
  GLDS16(zsrc, SC_OFF + w * 2048 + 1024);
  STAGE_XF(0);
  STAGE_MW(0, 0);
  STAGE_MW(1, 1);

  f32x4 acc[4] = {};

#define LDF4(off) (*(const f32x4*)(smem + (off)))
#define LDS8(off) (*(const short8*)(smem + (off)))
#define LDU4(off) (*(const u32x4*)(smem + (off)))
#define LDF(off) (*(const float*)(smem + (off)))

#pragma unroll 2
  for (int st = 0; st < NSTEPS; ++st) {
    const int cur = st & 1;
    // steady state: queue = [mw(st)x5, xf(st)x4, mw(st+1)x5]; vmcnt(5) retires
    // mw(st)+xf(st), keeps mw(st+1) in flight. Never drain the prefetch.
    if (st + 1 < NSTEPS) {
      asm volatile("s_waitcnt vmcnt(5)" ::: "memory");
    } else {
      asm volatile("s_waitcnt vmcnt(0)" ::: "memory");
    }
    __builtin_amdgcn_s_barrier();  // all waves' xf(st) tiles visible
    asm volatile("" ::: "memory");

    // ---- LDS -> regs (lane-linear b128: conflict-free) ----
    const unsigned mbase = (unsigned)(MB_OFF + cur * 16384 + w * 4096 + g4 * 1024 + r * 16);
    f32x4 mq[4];
#pragma unroll
    for (int sub = 0; sub < 2; ++sub)
#pragma unroll
      for (int jj = 0; jj < 2; ++jj) mq[sub * 2 + jj] = LDF4(mbase + sub * 512 + jj * 256);
    u32x4 wqv = LDU4(WQ_OFF + cur * 4096 + w * 1024 + l * 16);
    short8 xh[2][4], xl[2][4];
#pragma unroll
    for (int t = 0; t < 8; ++t) {
      xh[t >> 2][t & 3] = LDS8(XF_OFF + t * 2048 + l * 16);
      xl[t >> 2][t & 3] = LDS8(XF_OFF + t * 2048 + 1024 + l * 16);
    }
    const unsigned soff = (unsigned)(SC_OFF + w * 2048 + (4 * r + (st >> 2)) * 16 + (st & 3) * 4);
    float sc = LDF(soff);
    float zc = LDF(soff + 1024);

    asm volatile("s_waitcnt lgkmcnt(0)" ::: "memory");
    __builtin_amdgcn_s_barrier();  // everyone done reading xf/mask: buffers free
    asm volatile("" ::: "memory");

    // ---- issue next stages (xf first: vmcnt ledger depends on this order) ----
    if (st + 1 < NSTEPS) STAGE_XF(st + 1);
    if (st + 2 < NSTEPS) STAGE_MW(st + 2, cur);

    // ---- dequant + split-bf16 3-MFMA ----
    const float se = sc * mu2k;
    const float nz = -zc * se;
#pragma unroll
    for (int sub = 0; sub < 2; ++sub) {
      short8 bh, bl;
#pragma unroll
      for (int b = 0; b < 8; ++b) {
        unsigned wbits = (b < 4) ? wqv[sub * 2] : wqv[sub * 2 + 1];
        float qf = (float)((wbits >> (8 * (b & 3))) & 0xFFu);
        float mv = mq[sub * 2 + (b >> 2)][b & 3];
        float wv = fmaf(qf, se, nz) * mv;  // ((q-z)*s*mu2)*mask, fp32
        short h = f2bf(wv);
        bh[b] = h;
        bl[b] = f2bf(wv - bf2f(h));
      }
#pragma unroll
      for (int mb = 0; mb < 4; ++mb) {
        acc[mb] = __builtin_amdgcn_mfma_f32_16x16x32_bf16(xh[sub][mb], bh, acc[mb], 0, 0, 0);
        acc[mb] = __builtin_amdgcn_mfma_f32_16x16x32_bf16(xh[sub][mb], bl, acc[mb], 0, 0, 0);
        acc[mb] = __builtin_amdgcn_mfma_f32_16x16x32_bf16(xl[sub][mb], bh, acc[mb], 0, 0, 0);
      }
    }
  }

  // C/D layout (m89-verified): col=lane&15 -> output k, row=(lane>>4)*4+j -> token m
#pragma unroll
  for (int mb = 0; mb < 4; ++mb) {
#pragma unroll
    for (int j = 0; j < 4; ++j) {
      int m = mb * 16 + g4 * 4 + j;
      if constexpr (ATOMIC)
        atomicAdd(outp + (size_t)m * KDIM + kc, acc[mb][j]);
      else
        outp[(size_t)s * MK + (size_t)m * KDIM + kc] = acc[mb][j];
    }
  }
#undef GLDS16
#undef STAGE_MW
#undef STAGE_XF
#undef LDF4
#undef LDS8
#undef LDU4
#undef LDF
}

// cold fallback (W_q widened to int32): direct loads, same k-permute, no barriers.
template <bool ATOMIC>
__device__ void gemm_body_i32(const int* __restrict__ wq, const float* __restrict__ scales,
                              const float* __restrict__ zeros, const float* __restrict__ mask,
                              const float* __restrict__ mu2, const short* __restrict__ xfH,
                              const short* __restrict__ xfL, float* __restrict__ outp) {
  const int bx = blockIdx.x;
  const int kt = bx >> 3, s = bx & 7;
  const int k0 = kt * KT, n0 = s * NCHUNK;
  const int tid = threadIdx.x;
  const int w = tid >> 6, l = tid & 63;
  const int r = l & 15, g4 = l >> 4;
  const int kc = k0 + w * 16 + r;
  const float mu2k = mu2[kc];
  const float* mrow = mask + (size_t)kc * NDIM + n0 + g4 * 16;
  const int* qrow = wq + (size_t)kc * NDIM + n0 + g4 * 16;
  const float* srow = scales + (size_t)kc * NGRP + (n0 >> 6);
  const float* zrow = zeros + (size_t)kc * NGRP + (n0 >> 6);
  const short8* a8H = (const short8*)xfH;
  const short8* a8L = (const short8*)xfL;
  f32x4 acc[4] = {};
  for (int st = 0; st < NSTEPS; ++st) {
    const float se = srow[st] * mu2k, nz = -zrow[st] * se;
#pragma unroll
    for (int sub = 0; sub < 2; ++sub) {
      const int fo = st * 64 + sub * 8;
      f32x4 m0 = *(const f32x4*)(mrow + fo);
      f32x4 m1 = *(const f32x4*)(mrow + fo + 4);
      u32x4 qa = *(const u32x4*)(qrow + fo);
      u32x4 qb = *(const u32x4*)(qrow + fo + 4);
      short8 bh, bl;
#pragma unroll
      for (int i = 0; i < 8; ++i) {
        float qf = (float)(int)((i < 4) ? qa[i & 3] : qb[i & 3]);
        float mv = (i < 4) ? m0[i & 3] : m1[i & 3];
        float wv = fmaf(qf, se, nz) * mv;
        short h = f2bf(wv);
        bh[i] = h;
        bl[i] = f2bf(wv - bf2f(h));
      }
      const int F = s * 32 + st * 2 + sub;
      const short8* apH = a8H + (size_t)F * 256 + l;
      const short8* apL = a8L + (size_t)F * 256 + l;
#pragma unroll
      for (int mb = 0; mb < 4; ++mb) {
        short8 ah = apH[mb * 64], al = apL[mb * 64];
        acc[mb] = __builtin_amdgcn_mfma_f32_16x16x32_bf16(ah, bh, acc[mb], 0, 0, 0);
        acc[mb] = __builtin_amdgcn_mfma_f32_16x16x32_bf16(ah, bl, acc[mb], 0, 0, 0);
        acc[mb] = __builtin_amdgcn_mfma_f32_16x16x32_bf16(al, bh, acc[mb], 0, 0, 0);
      }
    }
  }
#pragma unroll
  for (int mb = 0; mb < 4; ++mb) {
#pragma unroll
    for (int j = 0; j < 4; ++j) {
      int m = mb * 16 + g4 * 4 + j;
      if constexpr (ATOMIC)
        atomicAdd(outp + (size_t)m * KDIM + kc, acc[mb][j]);
      else
        outp[(size_t)s * MK + (size_t)m * KDIM + kc] = acc[mb][j];
    }
  }
}

template <bool ATOMIC>
__global__ void __launch_bounds__(256, 2) gemm_kernel(
    const void* __restrict__ wq, const float* __restrict__ scales,
    const float* __restrict__ zeros, const float* __restrict__ mask,
    const float* __restrict__ mu2, const short* __restrict__ xfH,
    const short* __restrict__ xfL, float* __restrict__ outp) {
  __shared__ char smem[LDS_BYTES];
  // Self-detect W_q element width: packed int8 payload makes words > 15 a.s.
  // (values are 0..15, so a packed word exceeds 15 unless 3 upper bytes are 0).
  const unsigned* wqu = (const unsigned*)wq;
  bool i32m = true;
#pragma unroll
  for (int i = 0; i < 16; ++i) i32m &= (wqu[i] <= 15u);
  if (i32m)
    gemm_body_i32<ATOMIC>((const int*)wq, scales, zeros, mask, mu2, xfH, xfL, outp);
  else
    gemm_body_i8<ATOMIC>((const uint8_t*)wq, scales, zeros, mask, mu2, xfH, xfL, outp, smem);
}

extern "C" void kernel_launch(void* const* d_in, const int* in_sizes, int n_in,
                              void* d_out, int out_size, void* d_ws, size_t ws_size,
                              hipStream_t stream) {
  const float* x = (const float*)d_in[0];
  const void* wq = d_in[1];
  const float* scales = (const float*)d_in[2];
  const float* zeros = (const float*)d_in[3];
  const float* mask = (const float*)d_in[4];
  const float* mu1 = (const float*)d_in[5];
  const float* mu2 = (const float*)d_in[6];
  const float* bias = (const float*)d_in[7];
  float* out = (float*)d_out;
  short* xfH = (short*)d_ws;          // 1 MB
  short* xfL = xfH + XFRAG;           // 1 MB
  float* pw = (float*)(xfL + XFRAG);  // 16 MB split-K partials (ws path)

  const size_t need_ws = 2u * XFRAG * sizeof(short) + (size_t)SPLIT * MK * sizeof(float);
  const bool use_ws = ws_size >= need_ws;  // constant per process -> graph-safe

  prep_xf_kernel<<<dim3(256), dim3(256), 0, stream>>>(x, mu1, xfH, xfL);
  if (use_ws) {
    gemm_kernel<false><<<dim3((KDIM / KT) * SPLIT), dim3(256), 0, stream>>>(
        wq, scales, zeros, mask, mu2, xfH, xfL, pw);
    reduce_kernel<<<dim3(512), dim3(256), 0, stream>>>(pw, bias, out);
  } else {
    init_out_kernel<<<dim3(512), dim3(256), 0, stream>>>(bias, out);
    gemm_kernel<true><<<dim3((KDIM / KT) * SPLIT), dim3(256), 0, stream>>>(
        wq, scales, zeros, mask, mu2, xfH, xfL, out);
  }
}